// Round 1
// baseline (1630.792 us; speedup 1.0000x reference)
//
#include <hip/hip_runtime.h>
#include <hip/hip_bf16.h>
#include <math.h>

// ---------------- CSR build kernels ----------------

__global__ void degree_kernel(const int* __restrict__ dst, int* __restrict__ indeg, int E) {
    int e = blockIdx.x * 256 + threadIdx.x;
    if (e < E) atomicAdd(&indeg[dst[e]], 1);
}

__global__ void dinv_kernel(const int* __restrict__ indeg, float* __restrict__ dinv, int n) {
    int i = blockIdx.x * 256 + threadIdx.x;
    if (i < n) dinv[i] = 1.0f / sqrtf((float)indeg[i] + 1.0f);
}

// block scans 1024 elements (256 threads x 4)
__global__ void scan1_kernel(const int* __restrict__ indeg, int* __restrict__ row_ptr,
                             int* __restrict__ bsum, int n) {
    __shared__ int sh[256];
    int base = blockIdx.x * 1024 + threadIdx.x * 4;
    int v0 = (base + 0 < n) ? indeg[base + 0] : 0;
    int v1 = (base + 1 < n) ? indeg[base + 1] : 0;
    int v2 = (base + 2 < n) ? indeg[base + 2] : 0;
    int v3 = (base + 3 < n) ? indeg[base + 3] : 0;
    int tot = v0 + v1 + v2 + v3;
    sh[threadIdx.x] = tot;
    __syncthreads();
    int val = tot;
    for (int off = 1; off < 256; off <<= 1) {
        int add = 0;
        if ((int)threadIdx.x >= off) add = sh[threadIdx.x - off];
        __syncthreads();
        val += add;
        sh[threadIdx.x] = val;
        __syncthreads();
    }
    int excl = val - tot;  // exclusive prefix within block
    if (base + 0 < n) row_ptr[base + 0] = excl;
    if (base + 1 < n) row_ptr[base + 1] = excl + v0;
    if (base + 2 < n) row_ptr[base + 2] = excl + v0 + v1;
    if (base + 3 < n) row_ptr[base + 3] = excl + v0 + v1 + v2;
    if (threadIdx.x == 255) bsum[blockIdx.x] = val;
}

__global__ void scan2_kernel(int* __restrict__ bsum, int nb) {
    if (threadIdx.x == 0 && blockIdx.x == 0) {
        int a = 0;
        for (int i = 0; i < nb; ++i) { int t = bsum[i]; bsum[i] = a; a += t; }
        bsum[nb] = a;
    }
}

__global__ void scan3_kernel(int* __restrict__ row_ptr, const int* __restrict__ bsum,
                             int n, int nb) {
    int i = blockIdx.x * 256 + threadIdx.x;
    if (i < n) row_ptr[i] += bsum[i >> 10];
    if (i == 0) row_ptr[n] = bsum[nb];
}

__global__ void fill_kernel(const int* __restrict__ src, const int* __restrict__ dst,
                            const int* __restrict__ row_ptr, int* __restrict__ cnt,
                            int* __restrict__ col, int E) {
    int e = blockIdx.x * 256 + threadIdx.x;
    if (e < E) {
        int d = dst[e];
        int pos = row_ptr[d] + atomicAdd(&cnt[d], 1);
        col[pos] = src[e];
    }
}

// ---------------- dense matmul: out[N,OUTC] = x[N,64] @ W[64,OUTC] ----------------
// block: 256 threads, 16 rows/block; thread (q,c) computes 4 rows for column c.

template <int OUTC>
__global__ void mm_kernel(const float* __restrict__ x, const float* __restrict__ W,
                          float* __restrict__ out, int n) {
    __shared__ float Ws[64 * 64];
    __shared__ float xs[16 * 64];
    int tid = threadIdx.x;

    if (OUTC < 64) {
        for (int i = tid; i < 64 * 64; i += 256) Ws[i] = 0.0f;
        __syncthreads();
    }
    for (int i = tid; i < 64 * OUTC; i += 256) {
        int r = i / OUTC, c2 = i - r * OUTC;
        Ws[r * 64 + c2] = W[i];
    }
    int rowBase = blockIdx.x * 16;
    {
        int i = tid >> 4;   // staged row 0..15
        int fc = tid & 15;  // float4 column
        int r = rowBase + i;
        float4 val = make_float4(0.f, 0.f, 0.f, 0.f);
        if (r < n) val = ((const float4*)(x + (size_t)r * 64))[fc];
        ((float4*)(xs + i * 64))[fc] = val;
    }
    __syncthreads();

    int q = tid >> 6, c = tid & 63;
    float acc0 = 0.f, acc1 = 0.f, acc2 = 0.f, acc3 = 0.f;
    const float* xr = xs + q * 4 * 64;
#pragma unroll
    for (int k = 0; k < 64; ++k) {
        float wk = Ws[k * 64 + c];
        acc0 += xr[k] * wk;
        acc1 += xr[64 + k] * wk;
        acc2 += xr[128 + k] * wk;
        acc3 += xr[192 + k] * wk;
    }
    if (c < OUTC) {
        int r0 = rowBase + q * 4;
        if (r0 + 0 < n) out[(size_t)(r0 + 0) * OUTC + c] = acc0;
        if (r0 + 1 < n) out[(size_t)(r0 + 1) * OUTC + c] = acc1;
        if (r0 + 2 < n) out[(size_t)(r0 + 2) * OUTC + c] = acc2;
        if (r0 + 3 < n) out[(size_t)(r0 + 3) * OUTC + c] = acc3;
    }
}

// ---------------- aggregation: one wave per node, lanes = channels ----------------

template <int C, bool RELU, bool LSM>
__global__ void agg_kernel(const float* __restrict__ h, const int* __restrict__ row_ptr,
                           const int* __restrict__ col, const float* __restrict__ dinv,
                           const float* __restrict__ bias, float* __restrict__ out, int n) {
    int node = blockIdx.x * 4 + (threadIdx.x >> 6);
    if (node >= n) return;
    int lane = threadIdx.x & 63;
    bool act = (lane < C);
    int beg = row_ptr[node];
    int end = row_ptr[node + 1];
    float acc = 0.f;
    for (int e = beg; e < end; ++e) {
        int s = col[e];               // wave-uniform broadcast load
        float ds = dinv[s];
        if (act) acc += ds * h[(size_t)s * C + lane];
    }
    float di = dinv[node];
    float v = 0.f;
    if (act) {
        v = di * acc + di * di * h[(size_t)node * C + lane] + bias[lane];
        if (RELU) v = fmaxf(v, 0.f);
    }
    if (!LSM) {
        if (act) out[(size_t)node * C + lane] = v;
    } else {
        float m = act ? v : -INFINITY;
        for (int off = 32; off; off >>= 1) m = fmaxf(m, __shfl_xor(m, off));
        float ex = act ? expf(v - m) : 0.f;
        float ssum = ex;
        for (int off = 32; off; off >>= 1) ssum += __shfl_xor(ssum, off);
        if (act) out[(size_t)node * C + lane] = v - m - logf(ssum);
    }
}

// ---------------- launch ----------------

extern "C" void kernel_launch(void* const* d_in, const int* in_sizes, int n_in,
                              void* d_out, int out_size, void* d_ws, size_t ws_size,
                              hipStream_t stream) {
    const float* x  = (const float*)d_in[0];
    const int* ei   = (const int*)d_in[1];
    const float* W1 = (const float*)d_in[2];
    const float* b1 = (const float*)d_in[3];
    const float* Wh = (const float*)d_in[4];
    const float* bh = (const float*)d_in[5];
    const float* W2 = (const float*)d_in[6];
    const float* b2 = (const float*)d_in[7];
    float* out = (float*)d_out;

    const int N = in_sizes[0] / 64;
    const int E = in_sizes[1] / 2;
    const int NB = (N + 1023) / 1024;

    const int* srcp = ei;
    const int* dstp = ei + E;

    // workspace carve-up (256B aligned)
    size_t off = 0;
    auto alloc = [&](size_t bytes) {
        size_t o = off;
        off = (off + bytes + 255) & ~(size_t)255;
        return o;
    };
    char* ws = (char*)d_ws;
    int*   indeg   = (int*)(ws + alloc((size_t)N * 4));
    int*   row_ptr = (int*)(ws + alloc((size_t)(N + 1) * 4));
    int*   cnt     = (int*)(ws + alloc((size_t)N * 4));
    int*   bsum    = (int*)(ws + alloc((size_t)(NB + 1) * 4));
    float* dinv    = (float*)(ws + alloc((size_t)N * 4));
    int*   col     = (int*)(ws + alloc((size_t)E * 4));
    float* bufA    = (float*)(ws + alloc((size_t)N * 64 * 4));
    float* bufB    = (float*)(ws + alloc((size_t)N * 64 * 4));
    (void)ws_size;

    hipMemsetAsync(indeg, 0, (size_t)N * 4, stream);
    hipMemsetAsync(cnt, 0, (size_t)N * 4, stream);

    // CSR build
    degree_kernel<<<(E + 255) / 256, 256, 0, stream>>>(dstp, indeg, E);
    dinv_kernel<<<(N + 255) / 256, 256, 0, stream>>>(indeg, dinv, N);
    scan1_kernel<<<NB, 256, 0, stream>>>(indeg, row_ptr, bsum, N);
    scan2_kernel<<<1, 64, 0, stream>>>(bsum, NB);
    scan3_kernel<<<(N + 255) / 256, 256, 0, stream>>>(row_ptr, bsum, N, NB);
    fill_kernel<<<(E + 255) / 256, 256, 0, stream>>>(srcp, dstp, row_ptr, cnt, col, E);

    const int mmGrid = (N + 15) / 16;
    const int aggGrid = (N + 3) / 4;

    // layer 1: x @ W1 -> agg -> relu -> bufB
    mm_kernel<64><<<mmGrid, 256, 0, stream>>>(x, W1, bufA, N);
    agg_kernel<64, true, false><<<aggGrid, 256, 0, stream>>>(bufA, row_ptr, col, dinv, b1, bufB, N);
    // layer 2: bufB @ Wh -> agg -> relu -> bufB (via bufA)
    mm_kernel<64><<<mmGrid, 256, 0, stream>>>(bufB, Wh, bufA, N);
    agg_kernel<64, true, false><<<aggGrid, 256, 0, stream>>>(bufA, row_ptr, col, dinv, bh, bufB, N);
    // layer 3: bufB @ W2 -> agg -> log_softmax -> out
    mm_kernel<40><<<mmGrid, 256, 0, stream>>>(bufB, W2, bufA, N);
    agg_kernel<40, false, true><<<aggGrid, 256, 0, stream>>>(bufA, row_ptr, col, dinv, b2, out, N);
}

// Round 2
// 605.492 us; speedup vs baseline: 2.6933x; 2.6933x over previous
//
#include <hip/hip_runtime.h>
#include <hip/hip_bf16.h>
#include <math.h>

// ---------------- CSR build kernels ----------------

__global__ void degree_kernel(const int* __restrict__ dst, int* __restrict__ indeg, int E) {
    int e = blockIdx.x * 256 + threadIdx.x;
    if (e < E) atomicAdd(&indeg[dst[e]], 1);
}

__global__ void dinv_kernel(const int* __restrict__ indeg, float* __restrict__ dinv, int n) {
    int i = blockIdx.x * 256 + threadIdx.x;
    if (i < n) dinv[i] = 1.0f / sqrtf((float)indeg[i] + 1.0f);
}

// block scans 1024 elements (256 threads x 4)
__global__ void scan1_kernel(const int* __restrict__ indeg, int* __restrict__ row_ptr,
                             int* __restrict__ bsum, int n) {
    __shared__ int sh[256];
    int base = blockIdx.x * 1024 + threadIdx.x * 4;
    int v0 = (base + 0 < n) ? indeg[base + 0] : 0;
    int v1 = (base + 1 < n) ? indeg[base + 1] : 0;
    int v2 = (base + 2 < n) ? indeg[base + 2] : 0;
    int v3 = (base + 3 < n) ? indeg[base + 3] : 0;
    int tot = v0 + v1 + v2 + v3;
    sh[threadIdx.x] = tot;
    __syncthreads();
    int val = tot;
    for (int off = 1; off < 256; off <<= 1) {
        int add = 0;
        if ((int)threadIdx.x >= off) add = sh[threadIdx.x - off];
        __syncthreads();
        val += add;
        sh[threadIdx.x] = val;
        __syncthreads();
    }
    int excl = val - tot;  // exclusive prefix within block
    if (base + 0 < n) row_ptr[base + 0] = excl;
    if (base + 1 < n) row_ptr[base + 1] = excl + v0;
    if (base + 2 < n) row_ptr[base + 2] = excl + v0 + v1;
    if (base + 3 < n) row_ptr[base + 3] = excl + v0 + v1 + v2;
    if (threadIdx.x == 255) bsum[blockIdx.x] = val;
}

__global__ void scan2_kernel(int* __restrict__ bsum, int nb) {
    if (threadIdx.x == 0 && blockIdx.x == 0) {
        int a = 0;
        for (int i = 0; i < nb; ++i) { int t = bsum[i]; bsum[i] = a; a += t; }
        bsum[nb] = a;
    }
}

__global__ void scan3_kernel(int* __restrict__ row_ptr, const int* __restrict__ bsum,
                             int n, int nb) {
    int i = blockIdx.x * 256 + threadIdx.x;
    if (i < n) row_ptr[i] += bsum[i >> 10];
    if (i == 0) row_ptr[n] = bsum[nb];
}

__global__ void fill_kernel(const int* __restrict__ src, const int* __restrict__ dst,
                            const int* __restrict__ row_ptr, int* __restrict__ cnt,
                            int* __restrict__ col, int E) {
    int e = blockIdx.x * 256 + threadIdx.x;
    if (e < E) {
        int d = dst[e];
        int pos = row_ptr[d] + atomicAdd(&cnt[d], 1);
        col[pos] = src[e];
    }
}

// ---------------- fused layer: out = act( (Â·h) @ W + b ) ----------------
// One wave per node. Gather phase: lane = edge-slot(2b) x channel-quad(4b),
// float4 loads, 4 edges in flight. Then per-wave LDS round-trip and in-block
// matmul with W staged in LDS (zero-padded to 64x64).

template <int OUTC, bool RELU, bool LSM>
__global__ void gcn_layer(const float* __restrict__ h, const int* __restrict__ row_ptr,
                          const int* __restrict__ col, const float* __restrict__ dinv,
                          const float* __restrict__ bias, const float* __restrict__ W,
                          float* __restrict__ out, int n) {
    __shared__ float Ws[64 * 64];
    __shared__ float hs[4][64];
    int tid = threadIdx.x;

    if (OUTC < 64) {
        for (int i = tid; i < 64 * 64; i += 256) Ws[i] = 0.0f;
        __syncthreads();
    }
    for (int i = tid; i < 64 * OUTC; i += 256) {
        int r = i / OUTC, c2 = i - r * OUTC;
        Ws[r * 64 + c2] = W[i];
    }
    __syncthreads();

    int w = tid >> 6;       // wave 0..3
    int lane = tid & 63;
    int node = blockIdx.x * 4 + w;
    if (node >= n) return;

    int sub = lane >> 4;        // edge slot 0..3
    int ch4 = (lane & 15) * 4;  // channel base

    int beg = row_ptr[node];
    int end = row_ptr[node + 1];

    float4 acc = make_float4(0.f, 0.f, 0.f, 0.f);
    for (int e = beg + sub; e < end; e += 4) {
        int s = col[e];
        float ds = dinv[s];
        float4 hv = *(const float4*)(h + (size_t)s * 64 + ch4);
        acc.x += ds * hv.x;
        acc.y += ds * hv.y;
        acc.z += ds * hv.z;
        acc.w += ds * hv.w;
    }
    // reduce the 4 edge slots (butterfly over sub bits = lane bits 4,5)
    acc.x += __shfl_xor(acc.x, 16); acc.y += __shfl_xor(acc.y, 16);
    acc.z += __shfl_xor(acc.z, 16); acc.w += __shfl_xor(acc.w, 16);
    acc.x += __shfl_xor(acc.x, 32); acc.y += __shfl_xor(acc.y, 32);
    acc.z += __shfl_xor(acc.z, 32); acc.w += __shfl_xor(acc.w, 32);

    float di = dinv[node];
    if (sub == 0) {
        float4 self = *(const float4*)(h + (size_t)node * 64 + ch4);
        float4 a;
        a.x = di * acc.x + di * di * self.x;
        a.y = di * acc.y + di * di * self.y;
        a.z = di * acc.z + di * di * self.z;
        a.w = di * acc.w + di * di * self.w;
        *(float4*)(&hs[w][ch4]) = a;
    }
    // wave-local LDS write -> read; compiler inserts lgkmcnt wait, no barrier
    // needed (each wave touches only its own 256B slot).

    float v = (lane < OUTC) ? bias[lane] : 0.f;
#pragma unroll
    for (int k = 0; k < 64; ++k) {
        v += hs[w][k] * Ws[k * 64 + lane];   // broadcast + conflict-free
    }

    if (!LSM) {
        if (lane < OUTC) {
            if (RELU) v = fmaxf(v, 0.f);
            out[(size_t)node * OUTC + lane] = v;
        }
    } else {
        bool act = (lane < OUTC);
        float m = act ? v : -INFINITY;
        for (int off = 32; off; off >>= 1) m = fmaxf(m, __shfl_xor(m, off));
        float ex = act ? expf(v - m) : 0.f;
        float ssum = ex;
        for (int off = 32; off; off >>= 1) ssum += __shfl_xor(ssum, off);
        if (act) out[(size_t)node * OUTC + lane] = v - m - logf(ssum);
    }
}

// ---------------- launch ----------------

extern "C" void kernel_launch(void* const* d_in, const int* in_sizes, int n_in,
                              void* d_out, int out_size, void* d_ws, size_t ws_size,
                              hipStream_t stream) {
    const float* x  = (const float*)d_in[0];
    const int* ei   = (const int*)d_in[1];
    const float* W1 = (const float*)d_in[2];
    const float* b1 = (const float*)d_in[3];
    const float* Wh = (const float*)d_in[4];
    const float* bh = (const float*)d_in[5];
    const float* W2 = (const float*)d_in[6];
    const float* b2 = (const float*)d_in[7];
    float* out = (float*)d_out;

    const int N = in_sizes[0] / 64;
    const int E = in_sizes[1] / 2;
    const int NB = (N + 1023) / 1024;

    const int* srcp = ei;
    const int* dstp = ei + E;

    size_t off = 0;
    auto alloc = [&](size_t bytes) {
        size_t o = off;
        off = (off + bytes + 255) & ~(size_t)255;
        return o;
    };
    char* ws = (char*)d_ws;
    int*   indeg   = (int*)(ws + alloc((size_t)N * 4));
    int*   row_ptr = (int*)(ws + alloc((size_t)(N + 1) * 4));
    int*   cnt     = (int*)(ws + alloc((size_t)N * 4));
    int*   bsum    = (int*)(ws + alloc((size_t)(NB + 1) * 4));
    float* dinv    = (float*)(ws + alloc((size_t)N * 4));
    int*   col     = (int*)(ws + alloc((size_t)E * 4));
    float* bufA    = (float*)(ws + alloc((size_t)N * 64 * 4));
    float* bufB    = (float*)(ws + alloc((size_t)N * 64 * 4));
    (void)ws_size;

    hipMemsetAsync(indeg, 0, (size_t)N * 4, stream);
    hipMemsetAsync(cnt, 0, (size_t)N * 4, stream);

    // CSR build
    degree_kernel<<<(E + 255) / 256, 256, 0, stream>>>(dstp, indeg, E);
    dinv_kernel<<<(N + 255) / 256, 256, 0, stream>>>(indeg, dinv, N);
    scan1_kernel<<<NB, 256, 0, stream>>>(indeg, row_ptr, bsum, N);
    scan2_kernel<<<1, 64, 0, stream>>>(bsum, NB);
    scan3_kernel<<<(N + 255) / 256, 256, 0, stream>>>(row_ptr, bsum, N, NB);
    fill_kernel<<<(E + 255) / 256, 256, 0, stream>>>(srcp, dstp, row_ptr, cnt, col, E);

    const int layerGrid = (N + 3) / 4;

    // layer 1: relu( (Â·x) @ W1 + b1 ) -> bufA
    gcn_layer<64, true, false><<<layerGrid, 256, 0, stream>>>(x, row_ptr, col, dinv, b1, W1, bufA, N);
    // layer 2: relu( (Â·bufA) @ Wh + bh ) -> bufB
    gcn_layer<64, true, false><<<layerGrid, 256, 0, stream>>>(bufA, row_ptr, col, dinv, bh, Wh, bufB, N);
    // layer 3: log_softmax( (Â·bufB) @ W2 + b2 ) -> out
    gcn_layer<40, false, true><<<layerGrid, 256, 0, stream>>>(bufB, row_ptr, col, dinv, b2, W2, out, N);
}

// Round 3
// 568.405 us; speedup vs baseline: 2.8691x; 1.0652x over previous
//
#include <hip/hip_runtime.h>
#include <hip/hip_bf16.h>
#include <math.h>

// ---------------- CSR build kernels ----------------

__global__ void degree_kernel(const int* __restrict__ dst, int* __restrict__ indeg, int E) {
    int e = blockIdx.x * 256 + threadIdx.x;
    if (e < E) atomicAdd(&indeg[dst[e]], 1);
}

// block scans 1024 elements (256 threads x 4); also emits dinv = rsqrt(indeg+1)
__global__ void scan1_kernel(const int* __restrict__ indeg, int* __restrict__ row_ptr,
                             int* __restrict__ bsum, float* __restrict__ dinv, int n) {
    __shared__ int sh[256];
    int base = blockIdx.x * 1024 + threadIdx.x * 4;
    int v0 = (base + 0 < n) ? indeg[base + 0] : 0;
    int v1 = (base + 1 < n) ? indeg[base + 1] : 0;
    int v2 = (base + 2 < n) ? indeg[base + 2] : 0;
    int v3 = (base + 3 < n) ? indeg[base + 3] : 0;
    if (base + 0 < n) dinv[base + 0] = rsqrtf((float)v0 + 1.0f);
    if (base + 1 < n) dinv[base + 1] = rsqrtf((float)v1 + 1.0f);
    if (base + 2 < n) dinv[base + 2] = rsqrtf((float)v2 + 1.0f);
    if (base + 3 < n) dinv[base + 3] = rsqrtf((float)v3 + 1.0f);
    int tot = v0 + v1 + v2 + v3;
    sh[threadIdx.x] = tot;
    __syncthreads();
    int val = tot;
    for (int off = 1; off < 256; off <<= 1) {
        int add = 0;
        if ((int)threadIdx.x >= off) add = sh[threadIdx.x - off];
        __syncthreads();
        val += add;
        sh[threadIdx.x] = val;
        __syncthreads();
    }
    int excl = val - tot;  // exclusive prefix within block
    if (base + 0 < n) row_ptr[base + 0] = excl;
    if (base + 1 < n) row_ptr[base + 1] = excl + v0;
    if (base + 2 < n) row_ptr[base + 2] = excl + v0 + v1;
    if (base + 3 < n) row_ptr[base + 3] = excl + v0 + v1 + v2;
    if (threadIdx.x == 255) bsum[blockIdx.x] = val;
}

__global__ void scan2_kernel(int* __restrict__ bsum, int nb) {
    if (threadIdx.x == 0 && blockIdx.x == 0) {
        int a = 0;
        for (int i = 0; i < nb; ++i) { int t = bsum[i]; bsum[i] = a; a += t; }
        bsum[nb] = a;
    }
}

// finalize row_ptr and also emit the fill-cursor copy `next`
__global__ void scan3_kernel(int* __restrict__ row_ptr, int* __restrict__ next,
                             const int* __restrict__ bsum, int n, int nb) {
    int i = blockIdx.x * 256 + threadIdx.x;
    if (i < n) {
        int v = row_ptr[i] + bsum[i >> 10];
        row_ptr[i] = v;
        next[i] = v;
    }
    if (i == 0) row_ptr[n] = bsum[nb];
}

__global__ void fill_kernel(const int* __restrict__ src, const int* __restrict__ dst,
                            int* __restrict__ next, int* __restrict__ col, int E) {
    int e = blockIdx.x * 256 + threadIdx.x;
    if (e < E) {
        int pos = atomicAdd(&next[dst[e]], 1);
        col[pos] = src[e];
    }
}

// ---------------- fused layer: out = act( (Â·h) @ W + b ) ----------------
// One wave per node. Adjacency (col + dinv) prefetched into registers up
// front (self-loop folded in as virtual edge with weight di), so the inner
// loop has NO dependent loads: shfl index/weight, issue float4 h-row load.
// 8 edges in flight per iteration (2 chunks x 4 edge-slots).

template <int OUTC, bool RELU, bool LSM>
__launch_bounds__(256, 8)
__global__ void gcn_layer(const float* __restrict__ h, const int* __restrict__ row_ptr,
                          const int* __restrict__ col, const float* __restrict__ dinv,
                          const float* __restrict__ bias, const float* __restrict__ W,
                          float* __restrict__ out, int n) {
    __shared__ float Ws[64 * 64];
    __shared__ float hs[4][64];
    int tid = threadIdx.x;

    if (OUTC < 64) {
        for (int i = tid; i < 64 * 64; i += 256) Ws[i] = 0.0f;
        __syncthreads();
    }
    for (int i = tid; i < 64 * OUTC; i += 256) {
        int r = i / OUTC, c2 = i - r * OUTC;
        Ws[r * 64 + c2] = W[i];
    }
    __syncthreads();

    int w = tid >> 6;       // wave 0..3
    int lane = tid & 63;
    int node = blockIdx.x * 4 + w;
    if (node >= n) return;

    int sub = lane >> 4;        // edge slot 0..3
    int ch4 = (lane & 15) * 4;  // channel base

    int beg = row_ptr[node];
    int deg = row_ptr[node + 1] - beg;
    float di = dinv[node];
    int total = deg + 1;        // + virtual self edge (weight di)

    float4 acc = make_float4(0.f, 0.f, 0.f, 0.f);
    int base = 0;
    while (base < total) {
        // prefetch up to 64 virtual edges into registers (coalesced col load)
        int vi = base + lane;
        int idx = node;
        float dw = 0.f;
        if (vi < deg) {
            idx = col[beg + vi];
            dw = dinv[idx];
        } else if (vi == deg) {
            dw = di;            // self edge
        }
        int cnt = min(total - base, 64);
        for (int c0 = 0; c0 < cnt; c0 += 8) {
            int e0 = c0 + sub;
            int e1 = c0 + 4 + sub;
            int s0 = __shfl(idx, e0 & 63);
            float d0 = __shfl(dw, e0 & 63);
            int s1 = __shfl(idx, e1 & 63);
            float d1 = __shfl(dw, e1 & 63);
            if (e0 >= cnt) d0 = 0.f;
            if (e1 >= cnt) d1 = 0.f;
            float4 h0 = *(const float4*)(h + (size_t)s0 * 64 + ch4);
            float4 h1 = *(const float4*)(h + (size_t)s1 * 64 + ch4);
            acc.x += d0 * h0.x; acc.y += d0 * h0.y;
            acc.z += d0 * h0.z; acc.w += d0 * h0.w;
            acc.x += d1 * h1.x; acc.y += d1 * h1.y;
            acc.z += d1 * h1.z; acc.w += d1 * h1.w;
        }
        base += cnt;
    }
    // reduce the 4 edge slots (lane bits 4,5)
    acc.x += __shfl_xor(acc.x, 16); acc.y += __shfl_xor(acc.y, 16);
    acc.z += __shfl_xor(acc.z, 16); acc.w += __shfl_xor(acc.w, 16);
    acc.x += __shfl_xor(acc.x, 32); acc.y += __shfl_xor(acc.y, 32);
    acc.z += __shfl_xor(acc.z, 32); acc.w += __shfl_xor(acc.w, 32);

    if (sub == 0) {
        float4 a;
        a.x = di * acc.x; a.y = di * acc.y;
        a.z = di * acc.z; a.w = di * acc.w;
        *(float4*)(&hs[w][ch4]) = a;
    }
    // wave-local LDS write -> read; compiler inserts lgkmcnt wait, no barrier
    // needed (each wave touches only its own 256B slot).

    float v = (lane < OUTC) ? bias[lane] : 0.f;
#pragma unroll
    for (int k = 0; k < 64; ++k) {
        v += hs[w][k] * Ws[k * 64 + lane];   // broadcast + conflict-free
    }

    if (!LSM) {
        if (lane < OUTC) {
            if (RELU) v = fmaxf(v, 0.f);
            out[(size_t)node * OUTC + lane] = v;
        }
    } else {
        bool act = (lane < OUTC);
        float m = act ? v : -INFINITY;
        for (int off = 32; off; off >>= 1) m = fmaxf(m, __shfl_xor(m, off));
        float ex = act ? expf(v - m) : 0.f;
        float ssum = ex;
        for (int off = 32; off; off >>= 1) ssum += __shfl_xor(ssum, off);
        if (act) out[(size_t)node * OUTC + lane] = v - m - logf(ssum);
    }
}

// ---------------- launch ----------------

extern "C" void kernel_launch(void* const* d_in, const int* in_sizes, int n_in,
                              void* d_out, int out_size, void* d_ws, size_t ws_size,
                              hipStream_t stream) {
    const float* x  = (const float*)d_in[0];
    const int* ei   = (const int*)d_in[1];
    const float* W1 = (const float*)d_in[2];
    const float* b1 = (const float*)d_in[3];
    const float* Wh = (const float*)d_in[4];
    const float* bh = (const float*)d_in[5];
    const float* W2 = (const float*)d_in[6];
    const float* b2 = (const float*)d_in[7];
    float* out = (float*)d_out;

    const int N = in_sizes[0] / 64;
    const int E = in_sizes[1] / 2;
    const int NB = (N + 1023) / 1024;

    const int* srcp = ei;
    const int* dstp = ei + E;

    size_t off = 0;
    auto alloc = [&](size_t bytes) {
        size_t o = off;
        off = (off + bytes + 255) & ~(size_t)255;
        return o;
    };
    char* ws = (char*)d_ws;
    int*   indeg   = (int*)(ws + alloc((size_t)N * 4));
    int*   row_ptr = (int*)(ws + alloc((size_t)(N + 1) * 4));
    int*   next    = (int*)(ws + alloc((size_t)N * 4));
    int*   bsum    = (int*)(ws + alloc((size_t)(NB + 1) * 4));
    float* dinv    = (float*)(ws + alloc((size_t)N * 4));
    int*   col     = (int*)(ws + alloc((size_t)E * 4));
    float* bufA    = (float*)(ws + alloc((size_t)N * 64 * 4));
    float* bufB    = (float*)(ws + alloc((size_t)N * 64 * 4));
    (void)ws_size;

    hipMemsetAsync(indeg, 0, (size_t)N * 4, stream);

    // CSR build
    degree_kernel<<<(E + 255) / 256, 256, 0, stream>>>(dstp, indeg, E);
    scan1_kernel<<<NB, 256, 0, stream>>>(indeg, row_ptr, bsum, dinv, N);
    scan2_kernel<<<1, 64, 0, stream>>>(bsum, NB);
    scan3_kernel<<<(N + 255) / 256, 256, 0, stream>>>(row_ptr, next, bsum, N, NB);
    fill_kernel<<<(E + 255) / 256, 256, 0, stream>>>(srcp, dstp, next, col, E);

    const int layerGrid = (N + 3) / 4;

    // layer 1: relu( (Â·x) @ W1 + b1 ) -> bufA
    gcn_layer<64, true, false><<<layerGrid, 256, 0, stream>>>(x, row_ptr, col, dinv, b1, W1, bufA, N);
    // layer 2: relu( (Â·bufA) @ Wh + bh ) -> bufB
    gcn_layer<64, true, false><<<layerGrid, 256, 0, stream>>>(bufA, row_ptr, col, dinv, bh, Wh, bufB, N);
    // layer 3: log_softmax( (Â·bufB) @ W2 + b2 ) -> out
    gcn_layer<40, false, true><<<layerGrid, 256, 0, stream>>>(bufB, row_ptr, col, dinv, b2, W2, out, N);
}

// Round 4
// 432.044 us; speedup vs baseline: 3.7746x; 1.3156x over previous
//
#include <hip/hip_runtime.h>
#include <hip/hip_bf16.h>
#include <math.h>

#define NBUK 256
#define EPT 16   // edges per thread in hist/scatter kernels

__device__ __forceinline__ unsigned short bf16r(float f) {
    unsigned u = __builtin_bit_cast(unsigned, f);
    unsigned r = (u + 0x7fffu + ((u >> 16) & 1u)) >> 16;
    return (unsigned short)r;
}
__device__ __forceinline__ float bf_lo(unsigned u) {
    return __builtin_bit_cast(float, u << 16);
}
__device__ __forceinline__ float bf_hi(unsigned u) {
    return __builtin_bit_cast(float, u & 0xffff0000u);
}

// ---------------- CSR build via 256-bucket binning ----------------

__global__ void hist_kernel(const int* __restrict__ dst, int* __restrict__ bhist,
                            int E, int npb) {
    __shared__ int lh[NBUK];
    int tid = threadIdx.x;
    lh[tid] = 0;
    __syncthreads();
    int base = blockIdx.x * (256 * EPT);
    for (int k = 0; k < EPT; ++k) {
        int e = base + k * 256 + tid;
        if (e < E) atomicAdd(&lh[dst[e] / npb], 1);
    }
    __syncthreads();
    if (lh[tid] > 0) atomicAdd(&bhist[tid], lh[tid]);
}

__global__ void bscan_kernel(const int* __restrict__ bhist, int* __restrict__ bstart,
                             int* __restrict__ cursor) {
    __shared__ int sh[NBUK];
    int tid = threadIdx.x;
    int v = bhist[tid];
    sh[tid] = v;
    __syncthreads();
    int val = v;
    for (int off = 1; off < NBUK; off <<= 1) {
        int add = 0;
        if (tid >= off) add = sh[tid - off];
        __syncthreads();
        val += add;
        sh[tid] = val;
        __syncthreads();
    }
    int excl = val - v;
    bstart[tid] = excl;
    cursor[tid] = excl;
    if (tid == NBUK - 1) bstart[NBUK] = val;
}

__global__ void scat_kernel(const int* __restrict__ src, const int* __restrict__ dst,
                            int* __restrict__ cursor, int2* __restrict__ edge8,
                            int E, int npb) {
    __shared__ int lh[NBUK];
    __shared__ int lbase[NBUK];
    int tid = threadIdx.x;
    lh[tid] = 0;
    __syncthreads();
    int base = blockIdx.x * (256 * EPT);
    for (int k = 0; k < EPT; ++k) {
        int e = base + k * 256 + tid;
        if (e < E) atomicAdd(&lh[dst[e] / npb], 1);
    }
    __syncthreads();
    if (lh[tid] > 0) lbase[tid] = atomicAdd(&cursor[tid], lh[tid]);
    lh[tid] = 0;
    __syncthreads();
    for (int k = 0; k < EPT; ++k) {
        int e = base + k * 256 + tid;
        if (e < E) {
            int s = src[e], d = dst[e];
            int b = d / npb;
            int pos = lbase[b] + atomicAdd(&lh[b], 1);
            edge8[pos] = make_int2(s, d);
        }
    }
}

// one block per bucket: local degrees -> scan -> row_ptr/dinv -> fine scatter
__global__ void build_kernel(const int2* __restrict__ edge8, const int* __restrict__ bstart,
                             int* __restrict__ row_ptr, int* __restrict__ col,
                             float* __restrict__ dinv, int N, int E, int npb) {
    __shared__ int deg[512];
    __shared__ int sh[256];
    int b = blockIdx.x;
    int tid = threadIdx.x;
    int nodeBase = b * npb;
    int nn = N - nodeBase;
    if (nn > npb) nn = npb;
    if (nn < 0) nn = 0;
    int start = bstart[b];
    int cnt = bstart[b + 1] - start;

    deg[tid] = 0;
    deg[tid + 256] = 0;
    __syncthreads();
    for (int j = tid; j < cnt; j += 256) {
        int d = edge8[start + j].y;
        atomicAdd(&deg[d - nodeBase], 1);
    }
    __syncthreads();

    int i0 = tid * 2, i1 = i0 + 1;
    int v0 = deg[i0], v1 = deg[i1];
    int tot = v0 + v1;
    sh[tid] = tot;
    __syncthreads();
    int val = tot;
    for (int off = 1; off < 256; off <<= 1) {
        int add = 0;
        if (tid >= off) add = sh[tid - off];
        __syncthreads();
        val += add;
        sh[tid] = val;
        __syncthreads();
    }
    int excl = val - tot;

    if (i0 < nn) { row_ptr[nodeBase + i0] = start + excl;      dinv[nodeBase + i0] = rsqrtf((float)v0 + 1.0f); }
    if (i1 < nn) { row_ptr[nodeBase + i1] = start + excl + v0; dinv[nodeBase + i1] = rsqrtf((float)v1 + 1.0f); }
    if (b == NBUK - 1 && tid == 0) row_ptr[N] = E;
    // repurpose deg[] as absolute write cursors
    deg[i0] = start + excl;
    deg[i1] = start + excl + v0;
    __syncthreads();

    for (int j = tid; j < cnt; j += 256) {
        int2 e = edge8[start + j];
        int pos = atomicAdd(&deg[e.y - nodeBase], 1);
        col[pos] = e.x;
    }
}

// ---------------- fp32 -> bf16 feature convert ----------------

__global__ void cvt_kernel(const float* __restrict__ x, unsigned short* __restrict__ xb,
                           int n4) {
    int i = blockIdx.x * 256 + threadIdx.x;
    if (i < n4) {
        float4 v = *(const float4*)(x + (size_t)i * 4);
        ushort4 o;
        o.x = bf16r(v.x); o.y = bf16r(v.y); o.z = bf16r(v.z); o.w = bf16r(v.w);
        *(ushort4*)(xb + (size_t)i * 4) = o;
    }
}

// ---------------- fused layer: out = act( (Â·h) @ W + b ), h in bf16 --------
// One wave per node: lane = edge-slot(3b) x channel-oct(3b); each uint4 load
// grabs 8 bf16 channels, so one wave-instruction covers 8 edges. Adjacency
// prefetched into registers (self-loop folded as virtual edge, weight di);
// inner loop has no dependent loads. 16 edges in flight per iteration.

template <int OUTC, bool RELU, bool LSM>
__global__ void gcn_layer(const unsigned short* __restrict__ h, const int* __restrict__ row_ptr,
                          const int* __restrict__ col, const float* __restrict__ dinv,
                          const float* __restrict__ bias, const float* __restrict__ W,
                          void* __restrict__ outv, int n) {
    __shared__ float Ws[64 * 64];
    __shared__ float hs[4][64];
    int tid = threadIdx.x;

    if (OUTC < 64) {
        for (int i = tid; i < 64 * 64; i += 256) Ws[i] = 0.0f;
        __syncthreads();
    }
    for (int i = tid; i < 64 * OUTC; i += 256) {
        int r = i / OUTC, c2 = i - r * OUTC;
        Ws[r * 64 + c2] = W[i];
    }
    __syncthreads();

    int w = tid >> 6;
    int lane = tid & 63;
    int node = blockIdx.x * 4 + w;
    if (node >= n) return;

    int sub = lane >> 3;        // edge slot 0..7
    int ch8 = (lane & 7) * 8;   // channel base

    int beg = row_ptr[node];
    int deg = row_ptr[node + 1] - beg;
    float di = dinv[node];
    int total = deg + 1;        // + virtual self edge (weight di)

    float acc[8];
#pragma unroll
    for (int j = 0; j < 8; ++j) acc[j] = 0.f;

    int base = 0;
    while (base < total) {
        int vi = base + lane;
        int idx = node;
        float dw = 0.f;
        if (vi < deg) {
            idx = col[beg + vi];
            dw = dinv[idx];
        } else if (vi == deg) {
            dw = di;            // self edge
        }
        int cnt = min(total - base, 64);
        for (int c0 = 0; c0 < cnt; c0 += 16) {
            int e0 = c0 + sub;
            int e1 = c0 + 8 + sub;
            int s0 = __shfl(idx, e0 & 63);
            float d0 = __shfl(dw, e0 & 63);
            int s1 = __shfl(idx, e1 & 63);
            float d1 = __shfl(dw, e1 & 63);
            if (e0 >= cnt) d0 = 0.f;
            if (e1 >= cnt) d1 = 0.f;
            uint4 u0 = *(const uint4*)(h + (size_t)s0 * 64 + ch8);
            uint4 u1 = *(const uint4*)(h + (size_t)s1 * 64 + ch8);
            acc[0] += d0 * bf_lo(u0.x); acc[1] += d0 * bf_hi(u0.x);
            acc[2] += d0 * bf_lo(u0.y); acc[3] += d0 * bf_hi(u0.y);
            acc[4] += d0 * bf_lo(u0.z); acc[5] += d0 * bf_hi(u0.z);
            acc[6] += d0 * bf_lo(u0.w); acc[7] += d0 * bf_hi(u0.w);
            acc[0] += d1 * bf_lo(u1.x); acc[1] += d1 * bf_hi(u1.x);
            acc[2] += d1 * bf_lo(u1.y); acc[3] += d1 * bf_hi(u1.y);
            acc[4] += d1 * bf_lo(u1.z); acc[5] += d1 * bf_hi(u1.z);
            acc[6] += d1 * bf_lo(u1.w); acc[7] += d1 * bf_hi(u1.w);
        }
        base += cnt;
    }
    // reduce the 8 edge slots (lane bits 3,4,5)
#pragma unroll
    for (int off = 8; off <= 32; off <<= 1) {
#pragma unroll
        for (int j = 0; j < 8; ++j) acc[j] += __shfl_xor(acc[j], off);
    }

    if (sub == 0) {
#pragma unroll
        for (int j = 0; j < 8; ++j) hs[w][ch8 + j] = di * acc[j];
    }
    // wave-local LDS write -> read (each wave touches only its own 256B slot)

    float v = (lane < OUTC) ? bias[lane] : 0.f;
#pragma unroll
    for (int k = 0; k < 64; ++k) {
        v += hs[w][k] * Ws[k * 64 + lane];   // broadcast + conflict-free
    }

    if (!LSM) {
        if (lane < OUTC) {
            if (RELU) v = fmaxf(v, 0.f);
            ((unsigned short*)outv)[(size_t)node * OUTC + lane] = bf16r(v);
        }
    } else {
        bool act = (lane < OUTC);
        float m = act ? v : -INFINITY;
        for (int off = 32; off; off >>= 1) m = fmaxf(m, __shfl_xor(m, off));
        float ex = act ? expf(v - m) : 0.f;
        float ssum = ex;
        for (int off = 32; off; off >>= 1) ssum += __shfl_xor(ssum, off);
        if (act) ((float*)outv)[(size_t)node * OUTC + lane] = v - m - logf(ssum);
    }
}

// ---------------- launch ----------------

extern "C" void kernel_launch(void* const* d_in, const int* in_sizes, int n_in,
                              void* d_out, int out_size, void* d_ws, size_t ws_size,
                              hipStream_t stream) {
    const float* x  = (const float*)d_in[0];
    const int* ei   = (const int*)d_in[1];
    const float* W1 = (const float*)d_in[2];
    const float* b1 = (const float*)d_in[3];
    const float* Wh = (const float*)d_in[4];
    const float* bh = (const float*)d_in[5];
    const float* W2 = (const float*)d_in[6];
    const float* b2 = (const float*)d_in[7];
    float* out = (float*)d_out;

    const int N = in_sizes[0] / 64;
    const int E = in_sizes[1] / 2;
    const int npb = (N + NBUK - 1) / NBUK;   // nodes per bucket (<=512 required)

    const int* srcp = ei;
    const int* dstp = ei + E;

    size_t off = 0;
    auto alloc = [&](size_t bytes) {
        size_t o = off;
        off = (off + bytes + 255) & ~(size_t)255;
        return o;
    };
    char* ws = (char*)d_ws;
    int*   bhist   = (int*)(ws + alloc((size_t)NBUK * 4));
    int*   bstart  = (int*)(ws + alloc((size_t)(NBUK + 1) * 4));
    int*   cursor  = (int*)(ws + alloc((size_t)NBUK * 4));
    int*   row_ptr = (int*)(ws + alloc((size_t)(N + 1) * 4));
    float* dinv    = (float*)(ws + alloc((size_t)N * 4));
    int*   col     = (int*)(ws + alloc((size_t)E * 4));
    int2*  edge8   = (int2*)(ws + alloc((size_t)E * 8));
    unsigned short* xb   = (unsigned short*)(ws + alloc((size_t)N * 64 * 2));
    unsigned short* bufA = (unsigned short*)(ws + alloc((size_t)N * 64 * 2));
    unsigned short* bufB = (unsigned short*)(ws + alloc((size_t)N * 64 * 2));
    (void)ws_size;

    hipMemsetAsync(bhist, 0, (size_t)NBUK * 4, stream);

    const int ebGrid = (E + 256 * EPT - 1) / (256 * EPT);
    hist_kernel<<<ebGrid, 256, 0, stream>>>(dstp, bhist, E, npb);
    bscan_kernel<<<1, NBUK, 0, stream>>>(bhist, bstart, cursor);
    scat_kernel<<<ebGrid, 256, 0, stream>>>(srcp, dstp, cursor, edge8, E, npb);
    build_kernel<<<NBUK, 256, 0, stream>>>(edge8, bstart, row_ptr, col, dinv, N, E, npb);

    cvt_kernel<<<(N * 64 / 4 + 255) / 256, 256, 0, stream>>>(x, xb, N * 64 / 4);

    const int layerGrid = (N + 3) / 4;

    // layer 1: relu( (Â·x) @ W1 + b1 ) -> bufA (bf16)
    gcn_layer<64, true, false><<<layerGrid, 256, 0, stream>>>(xb, row_ptr, col, dinv, b1, W1, bufA, N);
    // layer 2: relu( (Â·bufA) @ Wh + bh ) -> bufB (bf16)
    gcn_layer<64, true, false><<<layerGrid, 256, 0, stream>>>(bufA, row_ptr, col, dinv, bh, Wh, bufB, N);
    // layer 3: log_softmax( (Â·bufB) @ W2 + b2 ) -> out (fp32)
    gcn_layer<40, false, true><<<layerGrid, 256, 0, stream>>>(bufB, row_ptr, col, dinv, b2, W2, out, N);
}

// Round 5
// 303.187 us; speedup vs baseline: 5.3788x; 1.4250x over previous
//
#include <hip/hip_runtime.h>
#include <hip/hip_bf16.h>
#include <math.h>

#define NBUK 256
#define EPT 16   // edges per thread in hist/scatter kernels

typedef __bf16 bf16x8 __attribute__((ext_vector_type(8)));
typedef float f32x4 __attribute__((ext_vector_type(4)));

__device__ __forceinline__ unsigned short bf16r(float f) {
    unsigned u = __builtin_bit_cast(unsigned, f);
    unsigned r = (u + 0x7fffu + ((u >> 16) & 1u)) >> 16;
    return (unsigned short)r;
}
__device__ __forceinline__ float bf_lo(unsigned u) {
    return __builtin_bit_cast(float, u << 16);
}
__device__ __forceinline__ float bf_hi(unsigned u) {
    return __builtin_bit_cast(float, u & 0xffff0000u);
}

// ---------------- CSR build via 256-bucket binning ----------------

__global__ void hist_kernel(const int* __restrict__ dst, int* __restrict__ bhist,
                            int E, int npb) {
    __shared__ int lh[NBUK];
    int tid = threadIdx.x;
    lh[tid] = 0;
    __syncthreads();
    int base = blockIdx.x * (256 * EPT);
    for (int k = 0; k < EPT; ++k) {
        int e = base + k * 256 + tid;
        if (e < E) atomicAdd(&lh[dst[e] / npb], 1);
    }
    __syncthreads();
    if (lh[tid] > 0) atomicAdd(&bhist[tid], lh[tid]);
}

__global__ void bscan_kernel(const int* __restrict__ bhist, int* __restrict__ bstart,
                             int* __restrict__ cursor) {
    __shared__ int sh[NBUK];
    int tid = threadIdx.x;
    int v = bhist[tid];
    sh[tid] = v;
    __syncthreads();
    int val = v;
    for (int off = 1; off < NBUK; off <<= 1) {
        int add = 0;
        if (tid >= off) add = sh[tid - off];
        __syncthreads();
        val += add;
        sh[tid] = val;
        __syncthreads();
    }
    int excl = val - v;
    bstart[tid] = excl;
    cursor[tid] = excl;
    if (tid == NBUK - 1) bstart[NBUK] = val;
}

__global__ void scat_kernel(const int* __restrict__ src, const int* __restrict__ dst,
                            int* __restrict__ cursor, int2* __restrict__ edge8,
                            int E, int npb) {
    __shared__ int lh[NBUK];
    __shared__ int lbase[NBUK];
    int tid = threadIdx.x;
    lh[tid] = 0;
    __syncthreads();
    int base = blockIdx.x * (256 * EPT);
    for (int k = 0; k < EPT; ++k) {
        int e = base + k * 256 + tid;
        if (e < E) atomicAdd(&lh[dst[e] / npb], 1);
    }
    __syncthreads();
    if (lh[tid] > 0) lbase[tid] = atomicAdd(&cursor[tid], lh[tid]);
    lh[tid] = 0;
    __syncthreads();
    for (int k = 0; k < EPT; ++k) {
        int e = base + k * 256 + tid;
        if (e < E) {
            int s = src[e], d = dst[e];
            int b = d / npb;
            int pos = lbase[b] + atomicAdd(&lh[b], 1);
            edge8[pos] = make_int2(s, d);
        }
    }
}

// one block per bucket: local degrees -> scan -> row_ptr/dinv -> fine scatter
__global__ void build_kernel(const int2* __restrict__ edge8, const int* __restrict__ bstart,
                             int* __restrict__ row_ptr, int* __restrict__ col,
                             float* __restrict__ dinv, int N, int E, int npb) {
    __shared__ int deg[512];
    __shared__ int sh[256];
    int b = blockIdx.x;
    int tid = threadIdx.x;
    int nodeBase = b * npb;
    int nn = N - nodeBase;
    if (nn > npb) nn = npb;
    if (nn < 0) nn = 0;
    int start = bstart[b];
    int cnt = bstart[b + 1] - start;

    deg[tid] = 0;
    deg[tid + 256] = 0;
    __syncthreads();
    for (int j = tid; j < cnt; j += 256) {
        int d = edge8[start + j].y;
        atomicAdd(&deg[d - nodeBase], 1);
    }
    __syncthreads();

    int i0 = tid * 2, i1 = i0 + 1;
    int v0 = deg[i0], v1 = deg[i1];
    int tot = v0 + v1;
    sh[tid] = tot;
    __syncthreads();
    int val = tot;
    for (int off = 1; off < 256; off <<= 1) {
        int add = 0;
        if (tid >= off) add = sh[tid - off];
        __syncthreads();
        val += add;
        sh[tid] = val;
        __syncthreads();
    }
    int excl = val - tot;

    if (i0 < nn) { row_ptr[nodeBase + i0] = start + excl;      dinv[nodeBase + i0] = rsqrtf((float)v0 + 1.0f); }
    if (i1 < nn) { row_ptr[nodeBase + i1] = start + excl + v0; dinv[nodeBase + i1] = rsqrtf((float)v1 + 1.0f); }
    if (b == NBUK - 1 && tid == 0) row_ptr[N] = E;
    // repurpose deg[] as absolute write cursors
    deg[i0] = start + excl;
    deg[i1] = start + excl + v0;
    __syncthreads();

    for (int j = tid; j < cnt; j += 256) {
        int2 e = edge8[start + j];
        int pos = atomicAdd(&deg[e.y - nodeBase], 1);
        col[pos] = e.x;
    }
}

// ---------------- fp32 -> bf16 feature convert ----------------

__global__ void cvt_kernel(const float* __restrict__ x, unsigned short* __restrict__ xb,
                           int n4) {
    int i = blockIdx.x * 256 + threadIdx.x;
    if (i < n4) {
        float4 v = *(const float4*)(x + (size_t)i * 4);
        ushort4 o;
        o.x = bf16r(v.x); o.y = bf16r(v.y); o.z = bf16r(v.z); o.w = bf16r(v.w);
        *(ushort4*)(xb + (size_t)i * 4) = o;
    }
}

// ---------------- weight pack: W -> MFMA B-fragment order, bf16 ----------------
// layout: wp[t*1024 + h*512 + lane*8 + j] = W[h*32 + (lane>>4)*8 + j][t*16 + (lane&15)]

__global__ void pack_kernel(const float* __restrict__ W1, const float* __restrict__ Wh,
                            const float* __restrict__ W2, unsigned short* __restrict__ wp1,
                            unsigned short* __restrict__ wph, unsigned short* __restrict__ wp2) {
    int i = blockIdx.x * 256 + threadIdx.x;   // grid 16 -> i in [0,4096)
    int j = i & 7;
    int lane = (i >> 3) & 63;
    int hh = (i >> 9) & 1;
    int t = i >> 10;
    int k = hh * 32 + (lane >> 4) * 8 + j;
    int cc = t * 16 + (lane & 15);
    wp1[i] = bf16r(W1[k * 64 + cc]);
    wph[i] = bf16r(Wh[k * 64 + cc]);
    if (t < 3) wp2[i] = bf16r(cc < 40 ? W2[k * 40 + cc] : 0.f);
}

// ---------------- aggregation: agg[node] = di*( sum dinv[s]*h[s] + di*h[node] ) ----
// One wave per node: lane = edge-slot(3b) x channel-oct(3b); uint4 = 8 bf16
// channels, 8 edges per wave-instruction, 16 edges in flight. Adjacency
// prefetched to registers; dead tail loads exec-masked.

__launch_bounds__(256, 8)
__global__ void agg_kernel(const unsigned short* __restrict__ h, const int* __restrict__ row_ptr,
                           const int* __restrict__ col, const float* __restrict__ dinv,
                           unsigned short* __restrict__ aggout, int n) {
    int tid = threadIdx.x;
    int lane = tid & 63;
    int node = blockIdx.x * 4 + (tid >> 6);
    if (node >= n) return;

    int sub = lane >> 3;        // edge slot 0..7
    int ch8 = (lane & 7) * 8;   // channel base

    int beg = row_ptr[node];
    int deg = row_ptr[node + 1] - beg;
    float di = dinv[node];
    int total = deg + 1;        // + virtual self edge (weight di)

    float acc[8];
#pragma unroll
    for (int j = 0; j < 8; ++j) acc[j] = 0.f;

    int base = 0;
    while (base < total) {
        int vi = base + lane;
        int idx = node;
        float dw = 0.f;
        if (vi < deg) {
            idx = col[beg + vi];
            dw = dinv[idx];
        } else if (vi == deg) {
            dw = di;            // self edge
        }
        int cnt = min(total - base, 64);
        for (int c0 = 0; c0 < cnt; c0 += 16) {
            int e0 = c0 + sub;
            int e1 = c0 + 8 + sub;
            int s0 = __shfl(idx, e0);
            float d0 = __shfl(dw, e0);
            int s1 = __shfl(idx, e1);
            float d1 = __shfl(dw, e1);
            uint4 u0 = make_uint4(0, 0, 0, 0);
            uint4 u1 = make_uint4(0, 0, 0, 0);
            if (e0 < cnt) u0 = *(const uint4*)(h + (size_t)s0 * 64 + ch8); else d0 = 0.f;
            if (e1 < cnt) u1 = *(const uint4*)(h + (size_t)s1 * 64 + ch8); else d1 = 0.f;
            acc[0] += d0 * bf_lo(u0.x); acc[1] += d0 * bf_hi(u0.x);
            acc[2] += d0 * bf_lo(u0.y); acc[3] += d0 * bf_hi(u0.y);
            acc[4] += d0 * bf_lo(u0.z); acc[5] += d0 * bf_hi(u0.z);
            acc[6] += d0 * bf_lo(u0.w); acc[7] += d0 * bf_hi(u0.w);
            acc[0] += d1 * bf_lo(u1.x); acc[1] += d1 * bf_hi(u1.x);
            acc[2] += d1 * bf_lo(u1.y); acc[3] += d1 * bf_hi(u1.y);
            acc[4] += d1 * bf_lo(u1.z); acc[5] += d1 * bf_hi(u1.z);
            acc[6] += d1 * bf_lo(u1.w); acc[7] += d1 * bf_hi(u1.w);
        }
        base += cnt;
    }
    // reduce the 8 edge slots (lane bits 3,4,5)
#pragma unroll
    for (int off = 8; off <= 32; off <<= 1) {
#pragma unroll
        for (int j = 0; j < 8; ++j) acc[j] += __shfl_xor(acc[j], off);
    }

    if (sub == 0) {
        unsigned p0 = (unsigned)bf16r(di * acc[0]) | ((unsigned)bf16r(di * acc[1]) << 16);
        unsigned p1 = (unsigned)bf16r(di * acc[2]) | ((unsigned)bf16r(di * acc[3]) << 16);
        unsigned p2 = (unsigned)bf16r(di * acc[4]) | ((unsigned)bf16r(di * acc[5]) << 16);
        unsigned p3 = (unsigned)bf16r(di * acc[6]) | ((unsigned)bf16r(di * acc[7]) << 16);
        *(uint4*)(aggout + (size_t)node * 64 + ch8) = make_uint4(p0, p1, p2, p3);
    }
}

// ---------------- MFMA epilogue GEMMs ----------------
// One wave per 16-node tile. A-frag: A[m=lane&15][k=quad*8+j] -> contiguous
// uint4 from agg buffer. B-frag from pre-packed wp. C/D: col=lane&15,
// row=quad*4+reg.

__global__ void gemm_relu_kernel(const unsigned short* __restrict__ A,
                                 const unsigned short* __restrict__ wp,
                                 const float* __restrict__ bias,
                                 unsigned short* __restrict__ out, int nTiles, int n) {
    int wv = blockIdx.x * 4 + (threadIdx.x >> 6);
    int lane = threadIdx.x & 63;
    if (wv >= nTiles) return;
    int q = lane >> 4, c = lane & 15;

    bf16x8 bfrag[4][2];
#pragma unroll
    for (int t = 0; t < 4; ++t)
#pragma unroll
        for (int hh = 0; hh < 2; ++hh)
            bfrag[t][hh] = *(const bf16x8*)(wp + t * 1024 + hh * 512 + lane * 8);
    float bs[4];
#pragma unroll
    for (int t = 0; t < 4; ++t) bs[t] = bias[t * 16 + c];

    int nodeBase = wv * 16;
    const unsigned short* arow = A + (size_t)(nodeBase + c) * 64 + q * 8;
    bf16x8 a0 = *(const bf16x8*)(arow);
    bf16x8 a1 = *(const bf16x8*)(arow + 32);

    f32x4 acc[4];
#pragma unroll
    for (int t = 0; t < 4; ++t) {
        f32x4 z = {0.f, 0.f, 0.f, 0.f};
        z = __builtin_amdgcn_mfma_f32_16x16x32_bf16(a0, bfrag[t][0], z, 0, 0, 0);
        z = __builtin_amdgcn_mfma_f32_16x16x32_bf16(a1, bfrag[t][1], z, 0, 0, 0);
        acc[t] = z;
    }

#pragma unroll
    for (int r = 0; r < 4; ++r) {
        int node = nodeBase + q * 4 + r;
        if (node < n) {
            unsigned short* orow = out + (size_t)node * 64;
#pragma unroll
            for (int t = 0; t < 4; ++t)
                orow[t * 16 + c] = bf16r(fmaxf(acc[t][r] + bs[t], 0.f));
        }
    }
}

__global__ void gemm_lsm_kernel(const unsigned short* __restrict__ A,
                                const unsigned short* __restrict__ wp,
                                const float* __restrict__ bias,
                                float* __restrict__ out, int nTiles, int n) {
    int wv = blockIdx.x * 4 + (threadIdx.x >> 6);
    int lane = threadIdx.x & 63;
    if (wv >= nTiles) return;
    int q = lane >> 4, c = lane & 15;
    bool v2ok = (c < 8);   // col 32+c < 40

    bf16x8 bfrag[3][2];
#pragma unroll
    for (int t = 0; t < 3; ++t)
#pragma unroll
        for (int hh = 0; hh < 2; ++hh)
            bfrag[t][hh] = *(const bf16x8*)(wp + t * 1024 + hh * 512 + lane * 8);
    float bs[3];
    bs[0] = bias[c];
    bs[1] = bias[16 + c];
    bs[2] = v2ok ? bias[32 + c] : 0.f;

    int nodeBase = wv * 16;
    const unsigned short* arow = A + (size_t)(nodeBase + c) * 64 + q * 8;
    bf16x8 a0 = *(const bf16x8*)(arow);
    bf16x8 a1 = *(const bf16x8*)(arow + 32);

    f32x4 acc[3];
#pragma unroll
    for (int t = 0; t < 3; ++t) {
        f32x4 z = {0.f, 0.f, 0.f, 0.f};
        z = __builtin_amdgcn_mfma_f32_16x16x32_bf16(a0, bfrag[t][0], z, 0, 0, 0);
        z = __builtin_amdgcn_mfma_f32_16x16x32_bf16(a1, bfrag[t][1], z, 0, 0, 0);
        acc[t] = z;
    }

#pragma unroll
    for (int r = 0; r < 4; ++r) {
        int node = nodeBase + q * 4 + r;
        if (node < n) {
            float v0 = acc[0][r] + bs[0];
            float v1 = acc[1][r] + bs[1];
            float v2 = v2ok ? (acc[2][r] + bs[2]) : -INFINITY;
            float m = fmaxf(fmaxf(v0, v1), v2);
#pragma unroll
            for (int off = 1; off <= 8; off <<= 1) m = fmaxf(m, __shfl_xor(m, off));
            float s = expf(v0 - m) + expf(v1 - m) + (v2ok ? expf(v2 - m) : 0.f);
#pragma unroll
            for (int off = 1; off <= 8; off <<= 1) s += __shfl_xor(s, off);
            float ls = m + logf(s);
            float* orow = out + (size_t)node * 40;
            orow[c] = v0 - ls;
            orow[16 + c] = v1 - ls;
            if (v2ok) orow[32 + c] = v2 - ls;
        }
    }
}

// ---------------- launch ----------------

extern "C" void kernel_launch(void* const* d_in, const int* in_sizes, int n_in,
                              void* d_out, int out_size, void* d_ws, size_t ws_size,
                              hipStream_t stream) {
    const float* x  = (const float*)d_in[0];
    const int* ei   = (const int*)d_in[1];
    const float* W1 = (const float*)d_in[2];
    const float* b1 = (const float*)d_in[3];
    const float* Wh = (const float*)d_in[4];
    const float* bh = (const float*)d_in[5];
    const float* W2 = (const float*)d_in[6];
    const float* b2 = (const float*)d_in[7];
    float* out = (float*)d_out;

    const int N = in_sizes[0] / 64;
    const int E = in_sizes[1] / 2;
    const int npb = (N + NBUK - 1) / NBUK;   // nodes per bucket (<=512 required)
    const int nTiles = (N + 15) / 16;
    const int Npad = nTiles * 16;

    const int* srcp = ei;
    const int* dstp = ei + E;

    size_t off = 0;
    auto alloc = [&](size_t bytes) {
        size_t o = off;
        off = (off + bytes + 255) & ~(size_t)255;
        return o;
    };
    char* ws = (char*)d_ws;
    int*   bhist   = (int*)(ws + alloc((size_t)NBUK * 4));
    int*   bstart  = (int*)(ws + alloc((size_t)(NBUK + 1) * 4));
    int*   cursor  = (int*)(ws + alloc((size_t)NBUK * 4));
    int*   row_ptr = (int*)(ws + alloc((size_t)(N + 1) * 4));
    float* dinv    = (float*)(ws + alloc((size_t)N * 4));
    int*   col     = (int*)(ws + alloc((size_t)E * 4));
    int2*  edge8   = (int2*)(ws + alloc((size_t)E * 8));
    unsigned short* wp1  = (unsigned short*)(ws + alloc(4096 * 2));
    unsigned short* wph  = (unsigned short*)(ws + alloc(4096 * 2));
    unsigned short* wp2  = (unsigned short*)(ws + alloc(3072 * 2));
    unsigned short* xb   = (unsigned short*)(ws + alloc((size_t)Npad * 64 * 2));
    unsigned short* aggA = (unsigned short*)(ws + alloc((size_t)Npad * 64 * 2));
    unsigned short* gA   = (unsigned short*)(ws + alloc((size_t)Npad * 64 * 2));
    (void)ws_size;

    hipMemsetAsync(bhist, 0, (size_t)NBUK * 4, stream);

    const int ebGrid = (E + 256 * EPT - 1) / (256 * EPT);
    hist_kernel<<<ebGrid, 256, 0, stream>>>(dstp, bhist, E, npb);
    bscan_kernel<<<1, NBUK, 0, stream>>>(bhist, bstart, cursor);
    scat_kernel<<<ebGrid, 256, 0, stream>>>(srcp, dstp, cursor, edge8, E, npb);
    build_kernel<<<NBUK, 256, 0, stream>>>(edge8, bstart, row_ptr, col, dinv, N, E, npb);

    cvt_kernel<<<(N * 64 / 4 + 255) / 256, 256, 0, stream>>>(x, xb, N * 64 / 4);
    pack_kernel<<<16, 256, 0, stream>>>(W1, Wh, W2, wp1, wph, wp2);

    const int aggGrid = (N + 3) / 4;
    const int gemmGrid = (nTiles + 3) / 4;

    // layer 1
    agg_kernel<<<aggGrid, 256, 0, stream>>>(xb, row_ptr, col, dinv, aggA, N);
    gemm_relu_kernel<<<gemmGrid, 256, 0, stream>>>(aggA, wp1, b1, gA, nTiles, N);
    // layer 2
    agg_kernel<<<aggGrid, 256, 0, stream>>>(gA, row_ptr, col, dinv, aggA, N);
    gemm_relu_kernel<<<gemmGrid, 256, 0, stream>>>(aggA, wph, bh, gA, nTiles, N);
    // layer 3
    agg_kernel<<<aggGrid, 256, 0, stream>>>(gA, row_ptr, col, dinv, aggA, N);
    gemm_lsm_kernel<<<gemmGrid, 256, 0, stream>>>(aggA, wp2, b2, out, nTiles, N);
}